// Round 6
// baseline (137.391 us; speedup 1.0000x reference)
//
#include <hip/hip_runtime.h>
#include <math.h>

// Match numpy (no FMA contraction) — mask boundary is bit-sensitive.
#pragma clang fp contract(off)

namespace {

constexpr int B = 12, H = 192, W = 640;
constexpr int HW  = H * W;        // 122880
constexpr int BHW = B * HW;       // 1474560
constexpr int NQ  = BHW / 4;      // 368640 float4 groups
constexpr float EPS = 1e-7f;

// kA / kM: 256-thread blocks, exactly one quad per thread, one generation.
constexpr int TA  = 256;
constexpr int GA  = NQ / TA;      // 1440 blocks
constexpr int BPB = (HW / 4) / TA; // 120 kA-blocks per batch (no block crosses batch)

constexpr int TR    = 6;          // fine winner-tile rows (spread DS-pipe load)
constexpr int TILES = H / TR;     // 32 tiles/batch
constexpr int TRW   = TR * W;     // 3840 targets/tile (u32 LDS = 15360 B)
constexpr int NBK   = B * TILES;  // 384 buckets == winner blocks
constexpr int GW    = NBK;
constexpr int GC    = 416;        // check blocks
constexpr int CGRID = GW + GC;    // 800
constexpr int TPB   = 1024;

// ws layout: cnt[NBK] u32 @ +0 | redA[GA*4] f32 @ +4096 | redB[GC*2] f32 @ +28672 |
//            bkt[NBK*HW] u32 @ +32768 (188.7 MB; ws = 256 MiB per constant poison fill)
// Winner semantics: LWW in linear index order == max-index-wins (proven
// bit-exact). kA bins every source into its (batch, cyi/6) bucket:
// entry = (n<<12)|pos, n = batch-local index (<2^17), pos = (cyi%6)*W+cxi
// (<3840, 12 bits). Winner block wb scans exactly cnt[wb] entries and
// resolves via LDS atomicMax(key n+1); bucket capacity HW each => no
// overflow possible (a batch emits exactly HW entries total).
// check[] scratch lives in out[0..BHW) between kBW and kM (proven pattern).

// P = (K @ pose)[:3,:] — arithmetic identical to reference einsum
// (left-assoc, contract off).
__device__ __forceinline__ void computeP(const float* __restrict__ Kb,
                                         const float* __restrict__ Po, float* P) {
#pragma unroll
    for (int i = 0; i < 3; ++i)
#pragma unroll
        for (int j = 0; j < 4; ++j) {
            float s = Kb[i*4+0] * Po[0*4+j];
            s = s + Kb[i*4+1] * Po[1*4+j];
            s = s + Kb[i*4+2] * Po[2*4+j];
            s = s + Kb[i*4+3] * Po[3*4+j];
            P[i*4+j] = s;
        }
}

__device__ __forceinline__ void static_flow_P(
    const float* __restrict__ iK, const float* __restrict__ P,
    int x, int y, float d, float& sx, float& sy)
{
    float fx = (float)x, fy = (float)y;
    float cam0 = iK[0]*fx + iK[1]*fy + iK[2];
    float cam1 = iK[4]*fx + iK[5]*fy + iK[6];
    float cam2 = iK[8]*fx + iK[9]*fy + iK[10];
    cam0 = d * cam0; cam1 = d * cam1; cam2 = d * cam2;
    float cp0 = P[0]*cam0 + P[1]*cam1 + P[2]*cam2  + P[3];
    float cp1 = P[4]*cam0 + P[5]*cam1 + P[6]*cam2  + P[7];
    float cp2 = P[8]*cam0 + P[9]*cam1 + P[10]*cam2 + P[11];
    float pz = cp2 + EPS;
    sx = cp0 / pz - fx;
    sy = cp1 / pz - fy;
}

__device__ __forceinline__ float norm01(float v, float mn, float mx) {
    return (2.0f * (v - mn)) / (mx - mn) - 1.0f;
}

// Block-wide min/max reduce + broadcast, parameterized on wave count.
template<int NW>
__device__ __forceinline__ void blockRed4T(float& a0, float& a1, float& a2, float& a3,
                                           float (*sred)[4], float* bc) {
    for (int off = 32; off; off >>= 1) {
        a0 = fminf(a0, __shfl_down(a0, off, 64));
        a1 = fmaxf(a1, __shfl_down(a1, off, 64));
        a2 = fminf(a2, __shfl_down(a2, off, 64));
        a3 = fmaxf(a3, __shfl_down(a3, off, 64));
    }
    int lane = threadIdx.x & 63, wv = threadIdx.x >> 6;
    if (lane == 0) { sred[wv][0]=a0; sred[wv][1]=a1; sred[wv][2]=a2; sred[wv][3]=a3; }
    __syncthreads();
    if (threadIdx.x == 0) {
#pragma unroll
        for (int w = 1; w < NW; ++w) {
            a0 = fminf(a0, sred[w][0]); a1 = fmaxf(a1, sred[w][1]);
            a2 = fminf(a2, sred[w][2]); a3 = fmaxf(a3, sred[w][3]);
        }
        bc[0]=a0; bc[1]=a1; bc[2]=a2; bc[3]=a3;
    }
    __syncthreads();
    a0=bc[0]; a1=bc[1]; a2=bc[2]; a3=bc[3];
}

template<int NW>
__device__ __forceinline__ void blockRed2T(float& a0, float& a1,
                                           float (*sred)[4], float* bc) {
    for (int off = 32; off; off >>= 1) {
        a0 = fminf(a0, __shfl_down(a0, off, 64));
        a1 = fmaxf(a1, __shfl_down(a1, off, 64));
    }
    int lane = threadIdx.x & 63, wv = threadIdx.x >> 6;
    if (lane == 0) { sred[wv][0]=a0; sred[wv][1]=a1; }
    __syncthreads();
    if (threadIdx.x == 0) {
#pragma unroll
        for (int w = 1; w < NW; ++w) {
            a0 = fminf(a0, sred[w][0]); a1 = fmaxf(a1, sred[w][1]);
        }
        bc[0]=a0; bc[1]=a1;
    }
    __syncthreads();
    a0=bc[0]; a1=bc[1];
}

// Dispatch 0: zero bucket counters (ws is poisoned between replays).
__global__ void kZ(unsigned* __restrict__ cnt) {
    cnt[threadIdx.x] = 0u;       // <<<1, NBK>>>
}

// Dispatch 1: one quad/thread — flow min/max + static-flow min/max partials
// into redA; bin each source into its (batch, tile) bucket.
__global__ void __launch_bounds__(TA)
kA(const float* __restrict__ flow, const float* __restrict__ depth,
   const float* __restrict__ Km, const float* __restrict__ invK,
   const float* __restrict__ pose,
   unsigned* __restrict__ cnt, unsigned* __restrict__ bkt,
   float* __restrict__ redA)
{
    __shared__ float sred[4][4];
    __shared__ float bc[4];
    __shared__ unsigned tcnt[TILES];
    __shared__ unsigned tbase[TILES];

    if (threadIdx.x < TILES) tcnt[threadIdx.x] = 0u;
    __syncthreads();

    int g  = blockIdx.x * TA + threadIdx.x;       // < NQ by construction
    int p0 = g * 4;
    int b  = p0 / HW;                             // == blockIdx.x / BPB
    float P[12];
    computeP(Km + b*16, pose + b*16, P);
    const float* iK = invK + b * 16;
    int n0 = p0 - b * HW;
    int y  = n0 / W;                 // quads never cross a row (W%4==0)
    int x0 = n0 - y * W;
    float4 fx4 = *(const float4*)(flow + b*2*HW + n0);
    float4 fy4 = *(const float4*)(flow + b*2*HW + HW + n0);
    float4 d4  = *(const float4*)(depth + p0);
    float fmn = fminf(fminf(fx4.x, fx4.y), fminf(fx4.z, fx4.w));
    float fmx = fmaxf(fmaxf(fx4.x, fx4.y), fmaxf(fx4.z, fx4.w));
    fmn = fminf(fmn, fminf(fminf(fy4.x, fy4.y), fminf(fy4.z, fy4.w)));
    fmx = fmaxf(fmx, fmaxf(fmaxf(fy4.x, fy4.y), fmaxf(fy4.z, fy4.w)));
    float smn = INFINITY, smx = -INFINITY;
    float fxa[4] = {fx4.x, fx4.y, fx4.z, fx4.w};
    float fya[4] = {fy4.x, fy4.y, fy4.z, fy4.w};
    float da[4]  = {d4.x, d4.y, d4.z, d4.w};
    int      t_j[4];
    unsigned off_j[4], e_j[4];
#pragma unroll
    for (int j = 0; j < 4; ++j) {
        float sx, sy;
        static_flow_P(iK, P, x0 + j, y, da[j], sx, sy);
        smn = fminf(smn, fminf(sx, sy));
        smx = fmaxf(smx, fmaxf(sx, sy));
        // target coords: round-half-even (rintf == jnp.round), clip
        int cxi = (int)rintf((float)(x0 + j) + fxa[j]);
        int cyi = (int)rintf((float)y + fya[j]);
        cxi = min(max(cxi, 0), W - 1);
        cyi = min(max(cyi, 0), H - 1);
        int t   = cyi / TR;                       // 0..31
        int pos = (cyi - t * TR) * W + cxi;       // < 3840 (12 bits)
        t_j[j]   = t;
        e_j[j]   = ((unsigned)(n0 + j) << 12) | (unsigned)pos;
        off_j[j] = atomicAdd(&tcnt[t], 1u);
    }
    __syncthreads();
    if (threadIdx.x < TILES)
        tbase[threadIdx.x] =
            atomicAdd(&cnt[b * TILES + threadIdx.x], tcnt[threadIdx.x]);
    __syncthreads();
#pragma unroll
    for (int j = 0; j < 4; ++j) {
        int idx = (b * TILES + t_j[j]) * HW + (int)(tbase[t_j[j]] + off_j[j]);
        bkt[idx] = e_j[j];
    }

    blockRed4T<4>(fmn, fmx, smn, smx, sred, bc);
    if (threadIdx.x == 0) {
        redA[blockIdx.x*4+0] = fmn; redA[blockIdx.x*4+1] = fmx;
        redA[blockIdx.x*4+2] = smn; redA[blockIdx.x*4+3] = smx;
    }
}

// Dispatch 2, block-specialized:
//  blocks [0,GW): winner blocks — scan exactly cnt[wb] bucket entries,
//    LDS atomicMax (key = n+1), in-LDS gather of exact payloads, write
//    bwd_flow + seg_ref directly.
//  blocks [GW,GW+GC): check blocks — re-reduce redA, compute check, stash
//    into out[0..BHW), partial min/max -> redB.
__global__ void __launch_bounds__(TPB)
kBW(const float* __restrict__ flow, const float* __restrict__ depth,
    const float* __restrict__ Km, const float* __restrict__ invK,
    const float* __restrict__ pose, const int* __restrict__ seg,
    const unsigned* __restrict__ cnt, const unsigned* __restrict__ bkt,
    const float* __restrict__ redA, float* __restrict__ redB,
    float* __restrict__ out)
{
    __shared__ unsigned smem[TRW];              // 15360 B
    if (blockIdx.x < GW) {
        // ---- winner block: exact-bucket scatter then in-LDS gather ----
        const int wb = blockIdx.x;
        const int b  = wb / TILES;              // wb >> 5
        const int t  = wb - b * TILES;          // wb & 31
        for (int i = threadIdx.x; i < TRW; i += TPB) smem[i] = 0u;
        __syncthreads();

        const unsigned count = cnt[wb];
        const unsigned* src = bkt + wb * HW;
        for (unsigned i = threadIdx.x; i < count; i += TPB) {
            unsigned e = src[i];
            atomicMax(&smem[e & 4095u], (e >> 12) + 1u);
        }
        __syncthreads();

        // in-LDS gather: tile targets n in [t*TRW, (t+1)*TRW)
        const float* fb = flow + b * 2 * HW;
        const int*   sb = seg + b * HW;
        const int    nbase = t * TRW;
        for (int q = threadIdx.x; q < TRW/4; q += TPB) {
            uint4 w4 = *(const uint4*)(smem + q*4);
            unsigned wa[4] = {w4.x, w4.y, w4.z, w4.w};
            float4 bx4, by4, sg4;
            float* bxa = (float*)&bx4;
            float* bya = (float*)&by4;
            float* sga = (float*)&sg4;
#pragma unroll
            for (int j = 0; j < 4; ++j) {
                float bx = 0.0f, by = 0.0f, sg = 0.0f;
                if (wa[j]) {
                    int nw = (int)wa[j] - 1;
                    bx = -fb[nw];
                    by = -fb[HW + nw];
                    sg = sb[nw] ? 1.0f : 0.0f;
                }
                bxa[j] = bx; bya[j] = by; sga[j] = sg;
            }
            int n = nbase + q * 4;
            *(float4*)(out + BHW + b*2*HW + n)      = bx4;  // bwd_flow x
            *(float4*)(out + BHW + b*2*HW + HW + n) = by4;  // bwd_flow y
            *(float4*)(out + 3*BHW + b*HW + n)      = sg4;  // seg_ref
        }
        return;
    }

    // ---- check block ----
    float (*sred)[4] = (float(*)[4])smem;
    float* bc = (float*)(smem + 64);

    float gfmn = INFINITY, gfmx = -INFINITY, gsmn = INFINITY, gsmx = -INFINITY;
    for (int i = threadIdx.x; i < GA; i += TPB) {
        gfmn = fminf(gfmn, redA[i*4+0]); gfmx = fmaxf(gfmx, redA[i*4+1]);
        gsmn = fminf(gsmn, redA[i*4+2]); gsmx = fmaxf(gsmx, redA[i*4+3]);
    }
    blockRed4T<16>(gfmn, gfmx, gsmn, gsmx, sred, bc);

    float cmn = INFINITY, cmx = -INFINITY;
    float P[12]; int bCur = -1;
    const int cb = blockIdx.x - GW;
    const int stride = GC * TPB;
    for (int g = cb * TPB + threadIdx.x; g < NQ; g += stride) {
        int p0 = g * 4;
        int b  = p0 / HW;
        if (b != bCur) { computeP(Km + b*16, pose + b*16, P); bCur = b; }
        const float* iK = invK + b * 16;
        int n0 = p0 - b * HW;
        int y  = n0 / W;
        int x0 = n0 - y * W;
        float4 fx4 = *(const float4*)(flow + b*2*HW + n0);
        float4 fy4 = *(const float4*)(flow + b*2*HW + HW + n0);
        float4 d4  = *(const float4*)(depth + p0);
        float fxa[4] = {fx4.x, fx4.y, fx4.z, fx4.w};
        float fya[4] = {fy4.x, fy4.y, fy4.z, fy4.w};
        float da[4]  = {d4.x, d4.y, d4.z, d4.w};
        float4 cv;
        float* cva = (float*)&cv;
#pragma unroll
        for (int j = 0; j < 4; ++j) {
            float sx, sy;
            static_flow_P(iK, P, x0 + j, y, da[j], sx, sy);
            float dx = norm01(fxa[j], gfmn, gfmx) - norm01(sx, gsmn, gsmx);
            float dy = norm01(fya[j], gfmn, gfmx) - norm01(sy, gsmn, gsmx);
            float c = sqrtf(dx*dx + dy*dy);
            cva[j] = c;
            cmn = fminf(cmn, c); cmx = fmaxf(cmx, c);
        }
        *(float4*)(out + p0) = cv;   // stash check (overwritten by kM)
    }
    blockRed2T<16>(cmn, cmx, sred, bc);
    if (threadIdx.x == 0) { redB[cb*2] = cmn; redB[cb*2+1] = cmx; }
}

// Dispatch 3: re-reduce redB + threshold stashed check in-place -> motion_mask.
__global__ void __launch_bounds__(TA)
kM(const float* __restrict__ redB, float* __restrict__ out)
{
    __shared__ float sred[4][4];
    __shared__ float bc[4];

    float gcmn = INFINITY, gcmx = -INFINITY;
    for (int i = threadIdx.x; i < GC; i += TA) {
        gcmn = fminf(gcmn, redB[2*i]); gcmx = fmaxf(gcmx, redB[2*i+1]);
    }
    blockRed2T<4>(gcmn, gcmx, sred, bc);

    int p0 = (blockIdx.x * TA + threadIdx.x) * 4;   // < BHW by construction
    float4 c4 = *(const float4*)(out + p0);          // stashed check
    float ca[4] = {c4.x, c4.y, c4.z, c4.w};
    float4 m4;
    float* ma = (float*)&m4;
#pragma unroll
    for (int j = 0; j < 4; ++j) {
        float cn = (ca[j] - gcmn) / (gcmx - gcmn);
        ma[j] = (cn < 0.98f) ? 1.0f : 0.0f;
    }
    *(float4*)(out + p0) = m4;                       // motion_mask
}

} // namespace

extern "C" void kernel_launch(void* const* d_in, const int* in_sizes, int n_in,
                              void* d_out, int out_size, void* d_ws, size_t ws_size,
                              hipStream_t stream) {
    const float* flow  = (const float*)d_in[0];
    const float* depth = (const float*)d_in[1];
    const float* Km    = (const float*)d_in[2];
    const float* invK  = (const float*)d_in[3];
    const float* pose  = (const float*)d_in[4];
    const int*   seg   = (const int*)d_in[5];
    float* out = (float*)d_out;

    unsigned* cnt  = (unsigned*)d_ws;                            // NBK u32
    float*    redA = (float*)((char*)d_ws + 4096);               // GA*4 f32
    float*    redB = (float*)((char*)d_ws + 28672);              // GC*2 f32
    unsigned* bkt  = (unsigned*)((char*)d_ws + 32768);           // NBK*HW u32 (188.7 MB)

    kZ <<<1,     NBK, 0, stream>>>(cnt);
    kA <<<GA,    TA,  0, stream>>>(flow, depth, Km, invK, pose, cnt, bkt, redA);
    kBW<<<CGRID, TPB, 0, stream>>>(flow, depth, Km, invK, pose, seg, cnt, bkt,
                                   redA, redB, out);
    kM <<<GA,    TA,  0, stream>>>(redB, out);
}

// Round 7
// 120.151 us; speedup vs baseline: 1.1435x; 1.1435x over previous
//
#include <hip/hip_runtime.h>
#include <math.h>

// Match numpy (no FMA contraction) — mask boundary is bit-sensitive.
#pragma clang fp contract(off)

namespace {

constexpr int B = 12, H = 192, W = 640;
constexpr int HW  = H * W;        // 122880
constexpr int BHW = B * HW;       // 1474560
constexpr int NQ  = BHW / 4;      // 368640 float4 groups
constexpr float EPS = 1e-7f;

// kA / kM: 256-thread blocks, exactly one quad per thread, one generation.
constexpr int TA  = 256;
constexpr int GA  = NQ / TA;      // 1440 blocks
constexpr int BPB = (HW / 4) / TA; // 120 kA-blocks per batch (blocks never cross batch)

constexpr int TR    = 6;          // fine winner-tile rows (spread DS-pipe load)
constexpr int TILES = H / TR;     // 32 tiles/batch
constexpr int TRW   = TR * W;     // 3840 targets/tile (u32 LDS = 15360 B)
constexpr int NBK   = B * TILES;  // 384 buckets == winner blocks
constexpr int GW    = NBK;
constexpr int GC    = 416;        // check blocks
constexpr int CGRID = GW + GC;    // 800
constexpr int TPB   = 1024;
constexpr int SEGCAP = 1024;      // = sources per kA block -> overflow impossible

// ws layout: redA[GA*4] f32 @ +0 | redB[GC*2] f32 @ +24576 |
//            cntA[GA*TILES] u32 @ +32768 (184 KB) |
//            bkt[NBK*BPB*SEGCAP] u32 @ +262144 (188.7 MB; ws = 256 MiB)
// Winner semantics: LWW in linear index order == max-index-wins (proven
// bit-exact across R0-R6). kA bins every source into a BLOCK-PRIVATE segment
// of its (batch, cyi/6) bucket: entry = ((n<<1|seg)<<12)|pos, n = batch-local
// index (17b), seg 1b, pos = (cyi%6)*W+cxi (12b). Rank within segment via LDS
// counters — NO global atomics, NO zeroing dispatch. Winner block (b,t) scans
// its 120 count-bounded segments and resolves via LDS atomicMax(key =
// (n<<1|seg)+1, monotone in n => identical winner). 0 = no writer.
// check[] scratch lives in out[0..BHW) between kBW and kM (proven pattern).
//
// XCD swizzle (R5-proven: FETCH 102->21.9 MB): winner blocks remapped so a
// batch's tile-blocks share an XCD L2 under round-robin dispatch
// (XCD = blockIdx%8): xcd=bi&7, k=bi>>3, wp=xcd*48+k (bijective over 384);
// b=wp>>5, t=wp&31 => each batch spans <=2 XCDs. R6 dropped this and gather
// FETCH exploded to 110 MB. Perf heuristic only — any mapping is correct.

// P = (K @ pose)[:3,:] — arithmetic identical to reference einsum
// (left-assoc, contract off).
__device__ __forceinline__ void computeP(const float* __restrict__ Kb,
                                         const float* __restrict__ Po, float* P) {
#pragma unroll
    for (int i = 0; i < 3; ++i)
#pragma unroll
        for (int j = 0; j < 4; ++j) {
            float s = Kb[i*4+0] * Po[0*4+j];
            s = s + Kb[i*4+1] * Po[1*4+j];
            s = s + Kb[i*4+2] * Po[2*4+j];
            s = s + Kb[i*4+3] * Po[3*4+j];
            P[i*4+j] = s;
        }
}

__device__ __forceinline__ void static_flow_P(
    const float* __restrict__ iK, const float* __restrict__ P,
    int x, int y, float d, float& sx, float& sy)
{
    float fx = (float)x, fy = (float)y;
    float cam0 = iK[0]*fx + iK[1]*fy + iK[2];
    float cam1 = iK[4]*fx + iK[5]*fy + iK[6];
    float cam2 = iK[8]*fx + iK[9]*fy + iK[10];
    cam0 = d * cam0; cam1 = d * cam1; cam2 = d * cam2;
    float cp0 = P[0]*cam0 + P[1]*cam1 + P[2]*cam2  + P[3];
    float cp1 = P[4]*cam0 + P[5]*cam1 + P[6]*cam2  + P[7];
    float cp2 = P[8]*cam0 + P[9]*cam1 + P[10]*cam2 + P[11];
    float pz = cp2 + EPS;
    sx = cp0 / pz - fx;
    sy = cp1 / pz - fy;
}

__device__ __forceinline__ float norm01(float v, float mn, float mx) {
    return (2.0f * (v - mn)) / (mx - mn) - 1.0f;
}

// Block-wide min/max reduce + broadcast, parameterized on wave count.
template<int NW>
__device__ __forceinline__ void blockRed4T(float& a0, float& a1, float& a2, float& a3,
                                           float (*sred)[4], float* bc) {
    for (int off = 32; off; off >>= 1) {
        a0 = fminf(a0, __shfl_down(a0, off, 64));
        a1 = fmaxf(a1, __shfl_down(a1, off, 64));
        a2 = fminf(a2, __shfl_down(a2, off, 64));
        a3 = fmaxf(a3, __shfl_down(a3, off, 64));
    }
    int lane = threadIdx.x & 63, wv = threadIdx.x >> 6;
    if (lane == 0) { sred[wv][0]=a0; sred[wv][1]=a1; sred[wv][2]=a2; sred[wv][3]=a3; }
    __syncthreads();
    if (threadIdx.x == 0) {
#pragma unroll
        for (int w = 1; w < NW; ++w) {
            a0 = fminf(a0, sred[w][0]); a1 = fmaxf(a1, sred[w][1]);
            a2 = fminf(a2, sred[w][2]); a3 = fmaxf(a3, sred[w][3]);
        }
        bc[0]=a0; bc[1]=a1; bc[2]=a2; bc[3]=a3;
    }
    __syncthreads();
    a0=bc[0]; a1=bc[1]; a2=bc[2]; a3=bc[3];
}

template<int NW>
__device__ __forceinline__ void blockRed2T(float& a0, float& a1,
                                           float (*sred)[4], float* bc) {
    for (int off = 32; off; off >>= 1) {
        a0 = fminf(a0, __shfl_down(a0, off, 64));
        a1 = fmaxf(a1, __shfl_down(a1, off, 64));
    }
    int lane = threadIdx.x & 63, wv = threadIdx.x >> 6;
    if (lane == 0) { sred[wv][0]=a0; sred[wv][1]=a1; }
    __syncthreads();
    if (threadIdx.x == 0) {
#pragma unroll
        for (int w = 1; w < NW; ++w) {
            a0 = fminf(a0, sred[w][0]); a1 = fmaxf(a1, sred[w][1]);
        }
        bc[0]=a0; bc[1]=a1;
    }
    __syncthreads();
    a0=bc[0]; a1=bc[1];
}

// Dispatch 1: one quad/thread — flow min/max + static-flow min/max partials
// into redA; bin each source (entry carries n, seg, pos) into its
// block-private bucket segment. No global atomics.
__global__ void __launch_bounds__(TA)
kA(const float* __restrict__ flow, const float* __restrict__ depth,
   const float* __restrict__ Km, const float* __restrict__ invK,
   const float* __restrict__ pose, const int* __restrict__ seg,
   unsigned* __restrict__ cntA, unsigned* __restrict__ bkt,
   float* __restrict__ redA)
{
    __shared__ float sred[4][4];
    __shared__ float bc[4];
    __shared__ unsigned tcnt[TILES];

    if (threadIdx.x < TILES) tcnt[threadIdx.x] = 0u;
    __syncthreads();

    int p0 = blockIdx.x * (TA * 4) + threadIdx.x * 4;   // < BHW
    int b  = blockIdx.x / BPB;
    int blkInB = blockIdx.x - b * BPB;
    float P[12];
    computeP(Km + b*16, pose + b*16, P);
    const float* iK = invK + b * 16;
    int n0 = p0 - b * HW;
    int y  = n0 / W;                 // quads never cross a row (W%4==0)
    int x0 = n0 - y * W;
    float4 fx4 = *(const float4*)(flow + b*2*HW + n0);
    float4 fy4 = *(const float4*)(flow + b*2*HW + HW + n0);
    float4 d4  = *(const float4*)(depth + p0);
    int4   s4  = *(const int4*)(seg + p0);
    float fmn = fminf(fminf(fx4.x, fx4.y), fminf(fx4.z, fx4.w));
    float fmx = fmaxf(fmaxf(fx4.x, fx4.y), fmaxf(fx4.z, fx4.w));
    fmn = fminf(fmn, fminf(fminf(fy4.x, fy4.y), fminf(fy4.z, fy4.w)));
    fmx = fmaxf(fmx, fmaxf(fmaxf(fy4.x, fy4.y), fmaxf(fy4.z, fy4.w)));
    float smn = INFINITY, smx = -INFINITY;
    float fxa[4] = {fx4.x, fx4.y, fx4.z, fx4.w};
    float fya[4] = {fy4.x, fy4.y, fy4.z, fy4.w};
    float da[4]  = {d4.x, d4.y, d4.z, d4.w};
    int   sa[4]  = {s4.x, s4.y, s4.z, s4.w};
    int      t_j[4];
    unsigned r_j[4], e_j[4];
#pragma unroll
    for (int j = 0; j < 4; ++j) {
        float sx, sy;
        static_flow_P(iK, P, x0 + j, y, da[j], sx, sy);
        smn = fminf(smn, fminf(sx, sy));
        smx = fmaxf(smx, fmaxf(sx, sy));
        // target coords: round-half-even (rintf == jnp.round), clip
        int cxi = (int)rintf((float)(x0 + j) + fxa[j]);
        int cyi = (int)rintf((float)y + fya[j]);
        cxi = min(max(cxi, 0), W - 1);
        cyi = min(max(cyi, 0), H - 1);
        int t   = cyi / TR;                       // 0..31
        int pos = (cyi - t * TR) * W + cxi;       // < 3840 (12 bits)
        unsigned ns = ((unsigned)(n0 + j) << 1) | (sa[j] ? 1u : 0u); // 18 bits
        t_j[j] = t;
        e_j[j] = (ns << 12) | (unsigned)pos;      // 30 bits
        r_j[j] = atomicAdd(&tcnt[t], 1u);         // rank within block segment
    }
    __syncthreads();
    if (threadIdx.x < TILES)
        cntA[blockIdx.x * TILES + threadIdx.x] = tcnt[threadIdx.x];
#pragma unroll
    for (int j = 0; j < 4; ++j) {
        size_t base = ((size_t)((b * TILES + t_j[j]) * BPB + blkInB)) * SEGCAP;
        bkt[base + r_j[j]] = e_j[j];
    }

    blockRed4T<4>(fmn, fmx, smn, smx, sred, bc);
    if (threadIdx.x == 0) {
        redA[blockIdx.x*4+0] = fmn; redA[blockIdx.x*4+1] = fmx;
        redA[blockIdx.x*4+2] = smn; redA[blockIdx.x*4+3] = smx;
    }
}

// Dispatch 2, block-specialized:
//  blocks [0,GW): winner blocks (XCD-swizzled) — scan own bucket's 120
//    count-bounded segments (wave-per-segment), LDS atomicMax, in-LDS gather
//    (flow only; seg rides in the key), write bwd_flow + seg_ref directly.
//  blocks [GW,GW+GC): check blocks — re-reduce redA, compute check, stash
//    into out[0..BHW), partial min/max -> redB.
__global__ void __launch_bounds__(TPB)
kBW(const float* __restrict__ flow, const float* __restrict__ depth,
    const float* __restrict__ Km, const float* __restrict__ invK,
    const float* __restrict__ pose,
    const unsigned* __restrict__ cntA, const unsigned* __restrict__ bkt,
    const float* __restrict__ redA, float* __restrict__ redB,
    float* __restrict__ out)
{
    __shared__ unsigned smem[TRW];              // 15360 B
    if (blockIdx.x < GW) {
        // ---- winner block ----
        // XCD-aware mapping: xcd = bi&7 (round-robin model), 48 blocks/XCD.
        const int xcd = blockIdx.x & 7;
        const int k   = blockIdx.x >> 3;        // 0..47
        const int wp  = xcd * 48 + k;           // bijective [0,384)
        const int b   = wp >> 5;                // /TILES
        const int t   = wp & 31;                // %TILES

        for (int i = threadIdx.x; i < TRW; i += TPB) smem[i] = 0u;
        __syncthreads();

        const int wv = threadIdx.x >> 6, lane = threadIdx.x & 63;
        for (int s = wv; s < BPB; s += 16) {
            unsigned c = cntA[(b * BPB + s) * TILES + t];
            const unsigned* src =
                bkt + ((size_t)((b * TILES + t) * BPB + s)) * SEGCAP;
            for (unsigned i = lane; i < c; i += 64) {
                unsigned e = src[i];
                atomicMax(&smem[e & 4095u], (e >> 12) + 1u);
            }
        }
        __syncthreads();

        // in-LDS gather: tile targets n in [t*TRW, (t+1)*TRW)
        const float* fb = flow + b * 2 * HW;
        const int    nbase = t * TRW;
        for (int q = threadIdx.x; q < TRW/4; q += TPB) {
            uint4 w4 = *(const uint4*)(smem + q*4);
            unsigned wa[4] = {w4.x, w4.y, w4.z, w4.w};
            float4 bx4, by4, sg4;
            float* bxa = (float*)&bx4;
            float* bya = (float*)&by4;
            float* sga = (float*)&sg4;
#pragma unroll
            for (int j = 0; j < 4; ++j) {
                float bx = 0.0f, by = 0.0f, sg = 0.0f;
                if (wa[j]) {
                    unsigned u = wa[j] - 1u;
                    int nw = (int)(u >> 1);
                    sg = (u & 1u) ? 1.0f : 0.0f;
                    bx = -fb[nw];
                    by = -fb[HW + nw];
                }
                bxa[j] = bx; bya[j] = by; sga[j] = sg;
            }
            int n = nbase + q * 4;
            *(float4*)(out + BHW + b*2*HW + n)      = bx4;  // bwd_flow x
            *(float4*)(out + BHW + b*2*HW + HW + n) = by4;  // bwd_flow y
            *(float4*)(out + 3*BHW + b*HW + n)      = sg4;  // seg_ref
        }
        return;
    }

    // ---- check block ----
    float (*sred)[4] = (float(*)[4])smem;
    float* bc = (float*)(smem + 64);

    float gfmn = INFINITY, gfmx = -INFINITY, gsmn = INFINITY, gsmx = -INFINITY;
    for (int i = threadIdx.x; i < GA; i += TPB) {
        gfmn = fminf(gfmn, redA[i*4+0]); gfmx = fmaxf(gfmx, redA[i*4+1]);
        gsmn = fminf(gsmn, redA[i*4+2]); gsmx = fmaxf(gsmx, redA[i*4+3]);
    }
    blockRed4T<16>(gfmn, gfmx, gsmn, gsmx, sred, bc);

    float cmn = INFINITY, cmx = -INFINITY;
    float P[12]; int bCur = -1;
    const int cb = blockIdx.x - GW;
    const int stride = GC * TPB;
    for (int g = cb * TPB + threadIdx.x; g < NQ; g += stride) {
        int p0 = g * 4;
        int b  = p0 / HW;
        if (b != bCur) { computeP(Km + b*16, pose + b*16, P); bCur = b; }
        const float* iK = invK + b * 16;
        int n0 = p0 - b * HW;
        int y  = n0 / W;
        int x0 = n0 - y * W;
        float4 fx4 = *(const float4*)(flow + b*2*HW + n0);
        float4 fy4 = *(const float4*)(flow + b*2*HW + HW + n0);
        float4 d4  = *(const float4*)(depth + p0);
        float fxa[4] = {fx4.x, fx4.y, fx4.z, fx4.w};
        float fya[4] = {fy4.x, fy4.y, fy4.z, fy4.w};
        float da[4]  = {d4.x, d4.y, d4.z, d4.w};
        float4 cv;
        float* cva = (float*)&cv;
#pragma unroll
        for (int j = 0; j < 4; ++j) {
            float sx, sy;
            static_flow_P(iK, P, x0 + j, y, da[j], sx, sy);
            float dx = norm01(fxa[j], gfmn, gfmx) - norm01(sx, gsmn, gsmx);
            float dy = norm01(fya[j], gfmn, gfmx) - norm01(sy, gsmn, gsmx);
            float c = sqrtf(dx*dx + dy*dy);
            cva[j] = c;
            cmn = fminf(cmn, c); cmx = fmaxf(cmx, c);
        }
        *(float4*)(out + p0) = cv;   // stash check (overwritten by kM)
    }
    blockRed2T<16>(cmn, cmx, sred, bc);
    if (threadIdx.x == 0) { redB[cb*2] = cmn; redB[cb*2+1] = cmx; }
}

// Dispatch 3: re-reduce redB + threshold stashed check in-place -> motion_mask.
__global__ void __launch_bounds__(TA)
kM(const float* __restrict__ redB, float* __restrict__ out)
{
    __shared__ float sred[4][4];
    __shared__ float bc[4];

    float gcmn = INFINITY, gcmx = -INFINITY;
    for (int i = threadIdx.x; i < GC; i += TA) {
        gcmn = fminf(gcmn, redB[2*i]); gcmx = fmaxf(gcmx, redB[2*i+1]);
    }
    blockRed2T<4>(gcmn, gcmx, sred, bc);

    int p0 = (blockIdx.x * TA + threadIdx.x) * 4;   // < BHW by construction
    float4 c4 = *(const float4*)(out + p0);          // stashed check
    float ca[4] = {c4.x, c4.y, c4.z, c4.w};
    float4 m4;
    float* ma = (float*)&m4;
#pragma unroll
    for (int j = 0; j < 4; ++j) {
        float cn = (ca[j] - gcmn) / (gcmx - gcmn);
        ma[j] = (cn < 0.98f) ? 1.0f : 0.0f;
    }
    *(float4*)(out + p0) = m4;                       // motion_mask
}

} // namespace

extern "C" void kernel_launch(void* const* d_in, const int* in_sizes, int n_in,
                              void* d_out, int out_size, void* d_ws, size_t ws_size,
                              hipStream_t stream) {
    const float* flow  = (const float*)d_in[0];
    const float* depth = (const float*)d_in[1];
    const float* Km    = (const float*)d_in[2];
    const float* invK  = (const float*)d_in[3];
    const float* pose  = (const float*)d_in[4];
    const int*   seg   = (const int*)d_in[5];
    float* out = (float*)d_out;

    float*    redA = (float*)d_ws;                               // GA*4 f32
    float*    redB = (float*)((char*)d_ws + 24576);              // GC*2 f32
    unsigned* cntA = (unsigned*)((char*)d_ws + 32768);           // GA*TILES u32 (184 KB)
    unsigned* bkt  = (unsigned*)((char*)d_ws + 262144);          // 188.7 MB

    kA <<<GA,    TA,  0, stream>>>(flow, depth, Km, invK, pose, seg,
                                   cntA, bkt, redA);
    kBW<<<CGRID, TPB, 0, stream>>>(flow, depth, Km, invK, pose,
                                   cntA, bkt, redA, redB, out);
    kM <<<GA,    TA,  0, stream>>>(redB, out);
}